// Round 2
// baseline (1109.812 us; speedup 1.0000x reference)
//
#include <hip/hip_runtime.h>

typedef unsigned short u16;
typedef __attribute__((ext_vector_type(8))) short bf16x8;
typedef __attribute__((ext_vector_type(4))) float f32x4;
typedef __attribute__((ext_vector_type(4))) u16 u16x4;

__device__ __forceinline__ u16 f2bf(float f) {
  unsigned int u = __builtin_bit_cast(unsigned int, f);
  return (u16)((u + 0x7FFFu + ((u >> 16) & 1u)) >> 16);
}

__device__ __forceinline__ f32x4 mfma16(bf16x8 a, bf16x8 b, f32x4 c) {
  return __builtin_amdgcn_mfma_f32_16x16x32_bf16(a, b, c, 0, 0, 0);
}

__device__ __forceinline__ void gload16(const void* g, void* l) {
  __builtin_amdgcn_global_load_lds(
      (const __attribute__((address_space(1))) unsigned int*)g,
      (__attribute__((address_space(3))) unsigned int*)l, 16, 0, 0);
}

// ---------------- pack kernels ----------------

__global__ void pack_x_kernel(const float* __restrict__ x, u16* __restrict__ xb) {
  const int i = blockIdx.x * 256 + threadIdx.x;  // one float4 per thread
  const float4 v = ((const float4*)x)[i];
  u16x4 o;
  o[0] = f2bf(v.x); o[1] = f2bf(v.y); o[2] = f2bf(v.z); o[3] = f2bf(v.w);
  ((u16x4*)xb)[i] = o;
}

// W: [512][4096] with col = k*8+h. Output Wp: [c = h*512+k][dd] bf16 (n-major, k-contig)
__global__ void pack_wqkv_kernel(const float* __restrict__ W, u16* __restrict__ Wp) {
  const int i = blockIdx.x * 256 + threadIdx.x;  // 2M threads
  const int c = i >> 9, dd = i & 511;
  Wp[i] = f2bf(W[(size_t)dd * 4096 + ((c & 511) << 3) + (c >> 9)]);
}

// Wo: [4096][512]. Output Wot: [n=512][k=4096] bf16
__global__ void pack_wo_kernel(const float* __restrict__ W, u16* __restrict__ Wp) {
  const int i = blockIdx.x * 256 + threadIdx.x;  // 2M threads
  Wp[i] = f2bf(W[(size_t)(i & 4095) * 512 + (i >> 12)]);
}

// ---------------- GEMM: C[M][N] = A[M][Kd] * B[N][Kd]^T (both k-contig, bf16) ----------------
// MODE 0: write bf16 to [bb][h][t][d] (QK proj, *scale); rows are (bb,t) with t = row&2047
// MODE 1: write bf16 transposed to Vt [bb][h][d][t]
// MODE 2: write fp32 + bias to [row][512]

template <int MODE>
__global__ __launch_bounds__(256, 2) void gemm_bf16(
    const u16* __restrict__ A, const u16* __restrict__ B,
    void* __restrict__ Cout, const float* __restrict__ bias,
    int Kd, float scale) {
  __shared__ u16 Al[128 * 64];
  __shared__ u16 Bl[128 * 64];
  const int tid = threadIdx.x;
  const int lane = tid & 63;
  const int w = tid >> 6, wm = w >> 1, wn = w & 1;
  const int l15 = lane & 15, lg = lane >> 4;
  const int m0 = blockIdx.y * 128, n0 = blockIdx.x * 128;

  f32x4 acc[4][4];
  const f32x4 zero = {0.f, 0.f, 0.f, 0.f};
#pragma unroll
  for (int i = 0; i < 4; ++i)
#pragma unroll
    for (int j = 0; j < 4; ++j) acc[i][j] = zero;

  const int nk = Kd >> 6;
  for (int kt = 0; kt < nk; ++kt) {
    __syncthreads();
    const int k0 = kt << 6;
#pragma unroll
    for (int s = 0; s < 4; ++s) {
      const int chunk = s * 256 + tid;
      const int row = chunk >> 3, c = chunk & 7;
      const int cs = c ^ (row & 7);
      gload16(A + (size_t)(m0 + row) * Kd + k0 + cs * 8, &Al[chunk * 8]);
    }
#pragma unroll
    for (int s = 0; s < 4; ++s) {
      const int chunk = s * 256 + tid;
      const int row = chunk >> 3, c = chunk & 7;
      const int cs = c ^ (row & 7);
      gload16(B + (size_t)(n0 + row) * Kd + k0 + cs * 8, &Bl[chunk * 8]);
    }
    __syncthreads();
#pragma unroll
    for (int kk = 0; kk < 2; ++kk) {
      bf16x8 af[4], bfr[4];
      const int ch = kk * 4 + lg;
#pragma unroll
      for (int i = 0; i < 4; ++i) {
        const int ar = wm * 64 + i * 16 + l15;
        af[i] = *(const bf16x8*)&Al[ar * 64 + ((ch ^ (ar & 7)) * 8)];
        const int br = wn * 64 + i * 16 + l15;
        bfr[i] = *(const bf16x8*)&Bl[br * 64 + ((ch ^ (br & 7)) * 8)];
      }
#pragma unroll
      for (int i = 0; i < 4; ++i)
#pragma unroll
        for (int j = 0; j < 4; ++j)
          acc[i][j] = mfma16(af[i], bfr[j], acc[i][j]);
    }
  }

#pragma unroll
  for (int i = 0; i < 4; ++i) {
    const int gr0 = m0 + wm * 64 + i * 16 + lg * 4;
#pragma unroll
    for (int j = 0; j < 4; ++j) {
      const int gc = n0 + wn * 64 + j * 16 + l15;
      if constexpr (MODE == 0) {
        u16* O = (u16*)Cout;
        const int h = gc >> 9, d = gc & 511;
#pragma unroll
        for (int r = 0; r < 4; ++r) {
          const int grr = gr0 + r;
          const int bb = grr >> 11, t = grr & 2047;
          O[((size_t)((bb * 8 + h) * 2048 + t) << 9) + d] = f2bf(acc[i][j][r] * scale);
        }
      } else if constexpr (MODE == 1) {
        u16* O = (u16*)Cout;
        const int h = gc >> 9, d = gc & 511;
        const int bb = gr0 >> 11, t = gr0 & 2047;
        u16x4 pk;
#pragma unroll
        for (int r = 0; r < 4; ++r) pk[r] = f2bf(acc[i][j][r]);
        *(u16x4*)&O[((size_t)((bb * 8 + h) * 512 + d) << 11) + t] = pk;
      } else {
        float* O = (float*)Cout;
        const float bv = bias[gc];
#pragma unroll
        for (int r = 0; r < 4; ++r)
          O[(size_t)(gr0 + r) * 512 + gc] = acc[i][j][r] + bv;
      }
    }
  }
}

// ---------------- flash attention ----------------
// Q,K: [bh][2048][512] bf16; Vt: [bh][512][2048] bf16; Og: [bb*2048+t][h*512+d] bf16
// grid: (32 qt, nbh). block = 4 waves, 64 Q rows (16/wave); KV block = 32; 64 steps.

__global__ __launch_bounds__(256, 2) void attn_kernel(
    const u16* __restrict__ Qg, const u16* __restrict__ Kg,
    const u16* __restrict__ Vtg, u16* __restrict__ Og) {
  __shared__ u16 K_lds[32 * 512];    // rows t (1024B), chunk swz: c ^ (row&7)
  __shared__ u16 Vt_lds[512 * 32];   // rows d (64B),  chunk swz: c ^ ((row>>1)&3)
  __shared__ u16 P_lds[4][16 * 32];  // per-wave, rows q (64B), same swz as Vt

  const int tid = threadIdx.x;
  const int lane = tid & 63;
  const int w = tid >> 6;
  const int l15 = lane & 15, lg = lane >> 4;
  const int bh = blockIdx.y, qt = blockIdx.x;

  const size_t bh_off = (size_t)bh * 2048 * 512;
  const u16* Qb = Qg + bh_off;
  const u16* Kb = Kg + bh_off;
  const u16* Vb = Vtg + bh_off;

  // Q rows for this wave, A-fragment layout: lane row = l15, k = lg*8 + 32*kk
  bf16x8 qf[16];
  {
    const int qrow = qt * 64 + w * 16 + l15;
    const u16* qp = Qb + (size_t)qrow * 512 + lg * 8;
#pragma unroll
    for (int kk = 0; kk < 16; ++kk) qf[kk] = *(const bf16x8*)(qp + kk * 32);
  }

  f32x4 acc[32];
  const f32x4 zero = {0.f, 0.f, 0.f, 0.f};
#pragma unroll
  for (int i = 0; i < 32; ++i) acc[i] = zero;
  float m[4], lsum[4];
#pragma unroll
  for (int r = 0; r < 4; ++r) { m[r] = -1e30f; lsum[r] = 0.f; }

  for (int step = 0; step < 64; ++step) {
    const int t0 = step * 32;
    __syncthreads();
#pragma unroll
    for (int s = 0; s < 8; ++s) {  // K tile: 32 x 512
      const int chunk = s * 256 + tid;
      const int row = chunk >> 6, c = chunk & 63;
      const int cs = c ^ (row & 7);
      gload16(Kb + (size_t)(t0 + row) * 512 + cs * 8, &K_lds[chunk * 8]);
    }
#pragma unroll
    for (int s = 0; s < 8; ++s) {  // Vt tile: 512 x 32
      const int chunk = s * 256 + tid;
      const int row = chunk >> 2, c = chunk & 3;
      const int cs = c ^ ((row >> 1) & 3);
      gload16(Vb + (size_t)row * 2048 + t0 + cs * 8, &Vt_lds[chunk * 8]);
    }
    __syncthreads();

    // S = Q K^T  (16 q x 32 kv per wave)
    f32x4 s0 = zero, s1 = zero;
#pragma unroll
    for (int kk = 0; kk < 16; ++kk) {
      const int ch = kk * 4 + lg;
      const int r0 = l15, r1 = 16 + l15;
      bf16x8 b0 = *(const bf16x8*)&K_lds[r0 * 512 + ((ch ^ (r0 & 7)) * 8)];
      bf16x8 b1 = *(const bf16x8*)&K_lds[r1 * 512 + ((ch ^ (r1 & 7)) * 8)];
      s0 = mfma16(qf[kk], b0, s0);
      s1 = mfma16(qf[kk], b1, s1);
    }

    // online softmax (rows = lg*4 + r; cols across lanes l15 and the 2 frags)
    float mloc[4];
#pragma unroll
    for (int r = 0; r < 4; ++r) mloc[r] = fmaxf(s0[r], s1[r]);
#pragma unroll
    for (int mask = 1; mask < 16; mask <<= 1) {
#pragma unroll
      for (int r = 0; r < 4; ++r)
        mloc[r] = fmaxf(mloc[r], __shfl_xor(mloc[r], mask, 64));
    }
    bool need = false;
    float mnew[4];
#pragma unroll
    for (int r = 0; r < 4; ++r) {
      mnew[r] = fmaxf(m[r], mloc[r]);
      need = need || (mnew[r] > m[r]);
    }
    if (__any(need)) {  // exact-skip: alpha==1 when max unchanged
      float al[4];
#pragma unroll
      for (int r = 0; r < 4; ++r) al[r] = __expf(m[r] - mnew[r]);
#pragma unroll
      for (int f = 0; f < 32; ++f)
#pragma unroll
        for (int r = 0; r < 4; ++r) acc[f][r] *= al[r];
#pragma unroll
      for (int r = 0; r < 4; ++r) { lsum[r] *= al[r]; m[r] = mnew[r]; }
    }

    // P = exp(S - m): write to per-wave LDS in A-fragment-friendly layout
#pragma unroll
    for (int nf = 0; nf < 2; ++nf) {
#pragma unroll
      for (int r = 0; r < 4; ++r) {
        const float sv = nf ? s1[r] : s0[r];
        const float p = __expf(sv - m[r]);
        lsum[r] += p;  // per-lane partial row-sum (reduced at the end)
        const int prow = lg * 4 + r;
        const int col = nf * 16 + l15;
        const int che = (col >> 3) ^ ((prow >> 1) & 3);
        P_lds[w][prow * 32 + che * 8 + (col & 7)] = f2bf(p);
      }
    }

    // O += P V   (A = P [q][kv], B = V via Vt rows)
    {
      const int arow = l15;
      const int ach = lg ^ ((arow >> 1) & 3);
      bf16x8 pa = *(const bf16x8*)&P_lds[w][arow * 32 + ach * 8];
#pragma unroll
      for (int nf = 0; nf < 32; ++nf) {
        const int vrow = nf * 16 + l15;
        const int vch = lg ^ ((vrow >> 1) & 3);
        bf16x8 vb = *(const bf16x8*)&Vt_lds[vrow * 32 + vch * 8];
        acc[nf] = mfma16(pa, vb, acc[nf]);
      }
    }
  }

  // finalize: full row-sums, normalize, store Og[bb*2048+t][h*512+d]
#pragma unroll
  for (int mask = 1; mask < 16; mask <<= 1) {
#pragma unroll
    for (int r = 0; r < 4; ++r) lsum[r] += __shfl_xor(lsum[r], mask, 64);
  }
  float inv[4];
#pragma unroll
  for (int r = 0; r < 4; ++r) inv[r] = 1.0f / lsum[r];

  const int bb = bh >> 3, h = bh & 7;
#pragma unroll
  for (int nf = 0; nf < 32; ++nf) {
    const int col = h * 512 + nf * 16 + l15;
#pragma unroll
    for (int r = 0; r < 4; ++r) {
      const int t = qt * 64 + w * 16 + lg * 4 + r;
      Og[(size_t)(bb * 2048 + t) * 4096 + col] = f2bf(acc[nf][r] * inv[r]);
    }
  }
}

// ---------------- launcher ----------------
// Workspace tiers (BB = batches processed per phase):
//   BB=4: 24 + 256 = 280 MiB    BB=2: 24 + 128 = 152 MiB    BB=1: 24 + 64 = 88 MiB

extern "C" void kernel_launch(void* const* d_in, const int* in_sizes, int n_in,
                              void* d_out, int out_size, void* d_ws, size_t ws_size,
                              hipStream_t stream) {
  const float* x = (const float*)d_in[0];
  const float* Wq = (const float*)d_in[1];
  const float* Wk = (const float*)d_in[2];
  const float* Wv = (const float*)d_in[3];
  const float* Wo = (const float*)d_in[4];
  const float* bo = (const float*)d_in[5];
  float* out = (float*)d_out;

  const size_t MB = 1ull << 20;
  int BB;
  if (ws_size >= 280 * MB) BB = 4;
  else if (ws_size >= 152 * MB) BB = 2;
  else BB = 1;

  char* ws = (char*)d_ws;
  u16* xb  = (u16*)(ws);                         // 8 MiB  [8192][512]
  u16* Wqp = (u16*)(ws + 8 * MB);                // 4 MiB  [4096][512]
  u16* Wkp = (u16*)(ws + 12 * MB);               // 4 MiB
  u16* Wvp = (u16*)(ws + 16 * MB);               // 4 MiB
  u16* Wot = (u16*)(ws + 20 * MB);               // 4 MiB  [512][4096]
  u16* Qg  = (u16*)(ws + 24 * MB);               // BB*16 MiB [bh][t][d]
  u16* Kg  = (u16*)(ws + (24 + 16 * BB) * MB);   // BB*16 MiB [bh][t][d]
  u16* Vtg = (u16*)(ws + (24 + 32 * BB) * MB);   // BB*16 MiB [bh][d][t]
  u16* Og  = (u16*)(ws + (24 + 48 * BB) * MB);   // BB*16 MiB [BB*2048][4096]

  pack_x_kernel<<<dim3(4096), dim3(256), 0, stream>>>(x, xb);
  pack_wqkv_kernel<<<dim3(8192), dim3(256), 0, stream>>>(Wq, Wqp);
  pack_wqkv_kernel<<<dim3(8192), dim3(256), 0, stream>>>(Wk, Wkp);
  pack_wqkv_kernel<<<dim3(8192), dim3(256), 0, stream>>>(Wv, Wvp);
  pack_wo_kernel<<<dim3(8192), dim3(256), 0, stream>>>(Wo, Wot);

  const float qk_scale = 0.21022410381342865f;  // 1 / 512^0.25

  const int nchunk = 4 / BB;
  for (int c = 0; c < nchunk; ++c) {
    const u16* Ax = xb + (size_t)c * BB * 2048 * 512;
    gemm_bf16<0><<<dim3(32, BB * 16), dim3(256), 0, stream>>>(Ax, Wqp, (void*)Qg, nullptr, 512, qk_scale);
    gemm_bf16<0><<<dim3(32, BB * 16), dim3(256), 0, stream>>>(Ax, Wkp, (void*)Kg, nullptr, 512, qk_scale);
    gemm_bf16<1><<<dim3(32, BB * 16), dim3(256), 0, stream>>>(Ax, Wvp, (void*)Vtg, nullptr, 512, 1.0f);

    attn_kernel<<<dim3(32, BB * 8), dim3(256), 0, stream>>>(Qg, Kg, Vtg, Og);

    gemm_bf16<2><<<dim3(4, BB * 16), dim3(256), 0, stream>>>(
        Og, Wot, (void*)(out + (size_t)c * BB * 2048 * 512), bo, 4096, 1.0f);
  }
}

// Round 4
// 892.529 us; speedup vs baseline: 1.2434x; 1.2434x over previous
//
#include <hip/hip_runtime.h>

typedef unsigned short u16;
typedef unsigned int u32;
typedef __attribute__((ext_vector_type(8))) short bf16x8;
typedef __attribute__((ext_vector_type(4))) float f32x4;
typedef __attribute__((ext_vector_type(16))) float f32x16;
typedef __attribute__((ext_vector_type(4))) u16 u16x4;
typedef __attribute__((ext_vector_type(4))) u32 u32x4;

__device__ __forceinline__ u16 f2bf(float f) {
  u32 u = __builtin_bit_cast(u32, f);
  return (u16)((u + 0x7FFFu + ((u >> 16) & 1u)) >> 16);
}

__device__ __forceinline__ f32x4 mfma16(bf16x8 a, bf16x8 b, f32x4 c) {
  return __builtin_amdgcn_mfma_f32_16x16x32_bf16(a, b, c, 0, 0, 0);
}
__device__ __forceinline__ f32x16 mfma32(bf16x8 a, bf16x8 b, f32x16 c) {
  return __builtin_amdgcn_mfma_f32_32x32x16_bf16(a, b, c, 0, 0, 0);
}

__device__ __forceinline__ void gload16(const void* g, void* l) {
  __builtin_amdgcn_global_load_lds(
      (const __attribute__((address_space(1))) unsigned int*)g,
      (__attribute__((address_space(3))) unsigned int*)l, 16, 0, 0);
}

__device__ __forceinline__ u32 cvtpk(float lo, float hi) {
  u32 r;
  asm volatile("v_cvt_pk_bf16_f32 %0, %1, %2" : "=v"(r) : "v"(lo), "v"(hi));
  return r;
}
__device__ __forceinline__ void pl32swap(u32& a, u32& b) {
  asm volatile("v_permlane32_swap_b32 %0, %1" : "+v"(a), "+v"(b));
}

// ---------------- pack kernels ----------------

__global__ void pack_x_kernel(const float* __restrict__ x, u16* __restrict__ xb) {
  const int i = blockIdx.x * 256 + threadIdx.x;
  const float4 v = ((const float4*)x)[i];
  u16x4 o;
  o[0] = f2bf(v.x); o[1] = f2bf(v.y); o[2] = f2bf(v.z); o[3] = f2bf(v.w);
  ((u16x4*)xb)[i] = o;
}

// W: [512][4096] col = k*8+h  ->  Wp: [h*512+k][dd]  (tiled LDS transpose)
__global__ void pack_wqkv_t(const float* __restrict__ W, u16* __restrict__ Wp) {
  __shared__ u16 tile[64][72];
  const int t = threadIdx.x;
  const int c0 = blockIdx.x * 64, dd0 = blockIdx.y * 64;
#pragma unroll
  for (int s = 0; s < 4; ++s) {
    const int r = s * 16 + (t >> 4);
    const int q = (t & 15) * 4;
    const float4 v = *(const float4*)&W[(size_t)(dd0 + r) * 4096 + c0 + q];
    tile[r][q + 0] = f2bf(v.x); tile[r][q + 1] = f2bf(v.y);
    tile[r][q + 2] = f2bf(v.z); tile[r][q + 3] = f2bf(v.w);
  }
  __syncthreads();
#pragma unroll
  for (int s = 0; s < 4; ++s) {
    const int cl = s * 16 + (t >> 4);
    const int u = t & 15;
    const int cg = c0 + cl;
    const int orow = (cg & 7) * 512 + (cg >> 3);
    u16x4 o;
#pragma unroll
    for (int i = 0; i < 4; ++i) o[i] = tile[u * 4 + i][cl];
    *(u16x4*)&Wp[(size_t)orow * 512 + dd0 + u * 4] = o;
  }
}

// Wo: [4096][512] -> Wot: [n=512][k=4096]
__global__ void pack_wo_t(const float* __restrict__ W, u16* __restrict__ Wp) {
  __shared__ u16 tile[64][72];
  const int t = threadIdx.x;
  const int k0 = blockIdx.x * 64, n0 = blockIdx.y * 64;
#pragma unroll
  for (int s = 0; s < 4; ++s) {
    const int r = s * 16 + (t >> 4);
    const int q = (t & 15) * 4;
    const float4 v = *(const float4*)&W[(size_t)(k0 + r) * 512 + n0 + q];
    tile[r][q + 0] = f2bf(v.x); tile[r][q + 1] = f2bf(v.y);
    tile[r][q + 2] = f2bf(v.z); tile[r][q + 3] = f2bf(v.w);
  }
  __syncthreads();
#pragma unroll
  for (int s = 0; s < 4; ++s) {
    const int cl = s * 16 + (t >> 4);
    const int u = t & 15;
    u16x4 o;
#pragma unroll
    for (int i = 0; i < 4; ++i) o[i] = tile[u * 4 + i][cl];
    *(u16x4*)&Wp[(size_t)(n0 + cl) * 4096 + k0 + u * 4] = o;
  }
}

// ---------------- GEMM: C[M][N] = A[M][Kd] * B[N][Kd]^T ----------------

template <int MODE>
__global__ __launch_bounds__(256, 2) void gemm_bf16(
    const u16* __restrict__ A, const u16* __restrict__ B,
    void* __restrict__ Cout, const float* __restrict__ bias,
    int Kd, float scale) {
  __shared__ u16 Al[128 * 64];
  __shared__ u16 Bl[128 * 64];
  const int tid = threadIdx.x;
  const int lane = tid & 63;
  const int w = tid >> 6, wm = w >> 1, wn = w & 1;
  const int l15 = lane & 15, lg = lane >> 4;
  const int m0 = blockIdx.y * 128, n0 = blockIdx.x * 128;

  f32x4 acc[4][4];
  const f32x4 zero = {0.f, 0.f, 0.f, 0.f};
#pragma unroll
  for (int i = 0; i < 4; ++i)
#pragma unroll
    for (int j = 0; j < 4; ++j) acc[i][j] = zero;

  const int nk = Kd >> 6;
  for (int kt = 0; kt < nk; ++kt) {
    __syncthreads();
    const int k0 = kt << 6;
#pragma unroll
    for (int s = 0; s < 4; ++s) {
      const int chunk = s * 256 + tid;
      const int row = chunk >> 3, c = chunk & 7;
      const int cs = c ^ (row & 7);
      gload16(A + (size_t)(m0 + row) * Kd + k0 + cs * 8, &Al[chunk * 8]);
    }
#pragma unroll
    for (int s = 0; s < 4; ++s) {
      const int chunk = s * 256 + tid;
      const int row = chunk >> 3, c = chunk & 7;
      const int cs = c ^ (row & 7);
      gload16(B + (size_t)(n0 + row) * Kd + k0 + cs * 8, &Bl[chunk * 8]);
    }
    __syncthreads();
#pragma unroll
    for (int kk = 0; kk < 2; ++kk) {
      bf16x8 af[4], bfr[4];
      const int ch = kk * 4 + lg;
#pragma unroll
      for (int i = 0; i < 4; ++i) {
        const int ar = wm * 64 + i * 16 + l15;
        af[i] = *(const bf16x8*)&Al[ar * 64 + ((ch ^ (ar & 7)) * 8)];
        const int br = wn * 64 + i * 16 + l15;
        bfr[i] = *(const bf16x8*)&Bl[br * 64 + ((ch ^ (br & 7)) * 8)];
      }
#pragma unroll
      for (int i = 0; i < 4; ++i)
#pragma unroll
        for (int j = 0; j < 4; ++j)
          acc[i][j] = mfma16(af[i], bfr[j], acc[i][j]);
    }
  }

#pragma unroll
  for (int i = 0; i < 4; ++i) {
    const int gr0 = m0 + wm * 64 + i * 16 + lg * 4;
#pragma unroll
    for (int j = 0; j < 4; ++j) {
      const int gc = n0 + wn * 64 + j * 16 + l15;
      if constexpr (MODE == 0) {
        u16* O = (u16*)Cout;
        const int h = gc >> 9, d = gc & 511;
#pragma unroll
        for (int r = 0; r < 4; ++r) {
          const int grr = gr0 + r;
          const int bb = grr >> 11, t = grr & 2047;
          O[((size_t)((bb * 8 + h) * 2048 + t) << 9) + d] = f2bf(acc[i][j][r] * scale);
        }
      } else if constexpr (MODE == 1) {
        u16* O = (u16*)Cout;
        const int h = gc >> 9, d = gc & 511;
        const int bb = gr0 >> 11, t = gr0 & 2047;
        u16x4 pk;
#pragma unroll
        for (int r = 0; r < 4; ++r) pk[r] = f2bf(acc[i][j][r]);
        *(u16x4*)&O[((size_t)((bb * 8 + h) * 512 + d) << 11) + t] = pk;
      } else {
        float* O = (float*)Cout;
        const float bv = bias[gc];
#pragma unroll
        for (int r = 0; r < 4; ++r)
          O[(size_t)(gr0 + r) * 512 + gc] = acc[i][j][r] + bv;
      }
    }
  }
}

// ---------------- flash attention v3: 32x32 MFMA, pair-split-k, f32 exchange ----------------
// Q,K: [bh][2048][512]; Vt: [bh][512][2048]; Og: [bb*2048+t][h*512+d]
// block = 4 waves = 2 pairs; pair owns 32 q rows; wave k/d-half = 256.
// KV block 32, 64 steps. Sxf: pair-wise F32 exchange of partial-k S^T.
// LDS = 32K (K) + 32K (Vt) + 16K (Sxf) = 81920 B exactly -> 2 blocks/CU.

__global__ __launch_bounds__(256, 2) void attn_kernel(
    const u16* __restrict__ Qg, const u16* __restrict__ Kg,
    const u16* __restrict__ Vtg, u16* __restrict__ Og, int nbh_pxcd) {
  __shared__ u16 K_lds[32 * 512];    // [kv][k]  chunk swz: c ^ (kv&31)
  __shared__ u16 Vt_lds[512 * 32];   // [d][kv]  chunk swz: c ^ ((d>>1)&3)
  __shared__ float Sxf[4][32][32];   // per-wave partial S^T, f32, slot-swizzled

  const int tid = threadIdx.x;
  const int lane = tid & 63;
  const int w = tid >> 6;
  const int pr = w >> 1, whalf = w & 1;
  const int l31 = lane & 31, hi = lane >> 5;

  // XCD-aware decode
  const int bid = blockIdx.x;
  const int x8 = bid & 7, rest = bid >> 3;
  const int qt = rest & 31;
  const int bh = x8 * nbh_pxcd + (rest >> 5);

  const size_t bh_off = (size_t)bh * 2048 * 512;
  const u16* Qb = Qg + bh_off;
  const u16* Kb = Kg + bh_off;
  const u16* Vb = Vtg + bh_off;

  // Q as B-fragments: lane holds Q[q = l31][k = whalf*256 + c*16 + hi*8 + j]
  const int qrow = qt * 64 + pr * 32 + l31;
  bf16x8 qf[16];
  {
    const u16* qp = Qb + (size_t)qrow * 512 + whalf * 256 + hi * 8;
#pragma unroll
    for (int c = 0; c < 16; ++c) qf[c] = *(const bf16x8*)(qp + c * 16);
  }

  f32x16 acc[8];
#pragma unroll
  for (int i = 0; i < 8; ++i) acc[i] = {};
  float m = -1e30f, lsum = 0.f;

  for (int step = 0; step < 64; ++step) {
    const int t0 = step * 32;
    __syncthreads();  // A: everyone done reading tiles + Sxf
#pragma unroll
    for (int s = 0; s < 8; ++s) {  // K tile 32x512
      const int chunk = s * 256 + tid;
      const int row = chunk >> 6, c = chunk & 63;
      const int cs = c ^ (row & 31);
      gload16(Kb + (size_t)(t0 + row) * 512 + cs * 8, &K_lds[chunk * 8]);
    }
#pragma unroll
    for (int s = 0; s < 8; ++s) {  // Vt tile 512x32
      const int chunk = s * 256 + tid;
      const int row = chunk >> 2, c = chunk & 3;
      const int cs = c ^ ((row >> 1) & 3);
      gload16(Vb + (size_t)row * 2048 + t0 + cs * 8, &Vt_lds[chunk * 8]);
    }
    __syncthreads();  // B: tiles ready

    // S^T partial = K_half · Q_half^T : rows=kv, cols=q
    f32x16 st = {};
#pragma unroll
    for (int c = 0; c < 16; ++c) {
      const int j = whalf * 32 + 2 * c + hi;
      const int pos = j ^ l31;
      bf16x8 kf = *(const bf16x8*)&K_lds[l31 * 512 + pos * 8];
      st = mfma32(kf, qf[c], st);
    }

    // exchange partial with pair partner in FULL F32 (slot-swizzled LDS)
    {
      float* sp = &Sxf[w][l31][0];
#pragma unroll
      for (int g = 0; g < 4; ++g) {
        const int slot = (2 * g + hi) ^ (l31 & 7);
        f32x4 v = {st[4 * g + 0], st[4 * g + 1], st[4 * g + 2], st[4 * g + 3]};
        *(f32x4*)&sp[slot * 4] = v;
      }
    }
    __syncthreads();  // C: partials visible
    float s[16];
    {
      const float* sp = &Sxf[w ^ 1][l31][0];
#pragma unroll
      for (int g = 0; g < 4; ++g) {
        const int slot = (2 * g + hi) ^ (l31 & 7);
        const f32x4 v = *(const f32x4*)&sp[slot * 4];
#pragma unroll
        for (int j = 0; j < 4; ++j) s[4 * g + j] = st[4 * g + j] + v[j];
      }
    }

    // online softmax: lane owns one q (l31), 16 of 32 kv
    float mx = s[0];
#pragma unroll
    for (int r = 1; r < 16; ++r) mx = fmaxf(mx, s[r]);
    mx = fmaxf(mx, __shfl_xor(mx, 32, 64));
    const float mnew = fmaxf(m, mx);
    if (__any(mnew > m)) {
      const float al = __expf(m - mnew);
#pragma unroll
      for (int i = 0; i < 8; ++i) acc[i] *= al;
      lsum *= al;
      m = mnew;
    }
    float p[16];
#pragma unroll
    for (int r = 0; r < 16; ++r) {
      p[r] = __expf(s[r] - m);
      lsum += p[r];
    }

    // P -> B-fragments (T12: cvt_pk + permlane32_swap)
    bf16x8 pf[2];
    {
      u32 wd[8];
#pragma unroll
      for (int g = 0; g < 4; ++g) {
        wd[2 * g] = cvtpk(p[4 * g + 0], p[4 * g + 1]);
        wd[2 * g + 1] = cvtpk(p[4 * g + 2], p[4 * g + 3]);
      }
      pl32swap(wd[0], wd[2]); pl32swap(wd[1], wd[3]);
      pl32swap(wd[4], wd[6]); pl32swap(wd[5], wd[7]);
      u32x4 f0 = {wd[0], wd[1], wd[2], wd[3]};
      u32x4 f1 = {wd[4], wd[5], wd[6], wd[7]};
      pf[0] = __builtin_bit_cast(bf16x8, f0);
      pf[1] = __builtin_bit_cast(bf16x8, f1);
    }

    // O^T += V^T · P : rows=d (wave's 256-half), cols=q
#pragma unroll
    for (int blk = 0; blk < 8; ++blk) {
      const int drow = whalf * 256 + blk * 32 + l31;
#pragma unroll
      for (int c = 0; c < 2; ++c) {
        const int pos = (2 * c + hi) ^ ((drow >> 1) & 3);
        bf16x8 vf = *(const bf16x8*)&Vt_lds[drow * 32 + pos * 8];
        acc[blk] = mfma32(vf, pf[c], acc[blk]);
      }
    }
  }

  // finalize
  lsum += __shfl_xor(lsum, 32, 64);
  const float inv = 1.0f / lsum;
  const int bb = bh >> 3, h = bh & 7;
  const int t = qt * 64 + pr * 32 + l31;
  u16* orow_p = Og + (size_t)(bb * 2048 + t) * 4096 + h * 512;
#pragma unroll
  for (int blk = 0; blk < 8; ++blk) {
    const int dbase = whalf * 256 + blk * 32 + 4 * hi;
#pragma unroll
    for (int g = 0; g < 4; ++g) {
      u16x4 pk;
#pragma unroll
      for (int i = 0; i < 4; ++i) pk[i] = f2bf(acc[blk][4 * g + i] * inv);
      *(u16x4*)(orow_p + dbase + 8 * g) = pk;
    }
  }
}

// ---------------- launcher ----------------

extern "C" void kernel_launch(void* const* d_in, const int* in_sizes, int n_in,
                              void* d_out, int out_size, void* d_ws, size_t ws_size,
                              hipStream_t stream) {
  const float* x = (const float*)d_in[0];
  const float* Wq = (const float*)d_in[1];
  const float* Wk = (const float*)d_in[2];
  const float* Wv = (const float*)d_in[3];
  const float* Wo = (const float*)d_in[4];
  const float* bo = (const float*)d_in[5];
  float* out = (float*)d_out;

  const size_t MB = 1ull << 20;
  int BB;
  if (ws_size >= 280 * MB) BB = 4;
  else if (ws_size >= 152 * MB) BB = 2;
  else BB = 1;

  char* ws = (char*)d_ws;
  u16* xb  = (u16*)(ws);
  u16* Wqp = (u16*)(ws + 8 * MB);
  u16* Wkp = (u16*)(ws + 12 * MB);
  u16* Wvp = (u16*)(ws + 16 * MB);
  u16* Wot = (u16*)(ws + 20 * MB);
  u16* Qg  = (u16*)(ws + 24 * MB);
  u16* Kg  = (u16*)(ws + (24 + 16 * BB) * MB);
  u16* Vtg = (u16*)(ws + (24 + 32 * BB) * MB);
  u16* Og  = (u16*)(ws + (24 + 48 * BB) * MB);

  pack_x_kernel<<<dim3(4096), dim3(256), 0, stream>>>(x, xb);
  pack_wqkv_t<<<dim3(64, 8), dim3(256), 0, stream>>>(Wq, Wqp);
  pack_wqkv_t<<<dim3(64, 8), dim3(256), 0, stream>>>(Wk, Wkp);
  pack_wqkv_t<<<dim3(64, 8), dim3(256), 0, stream>>>(Wv, Wvp);
  pack_wo_t<<<dim3(64, 8), dim3(256), 0, stream>>>(Wo, Wot);

  const float qk_scale = 0.21022410381342865f;  // 1 / 512^0.25

  const int nchunk = 4 / BB;
  for (int c = 0; c < nchunk; ++c) {
    const u16* Ax = xb + (size_t)c * BB * 2048 * 512;
    gemm_bf16<0><<<dim3(32, BB * 16), dim3(256), 0, stream>>>(Ax, Wqp, (void*)Qg, nullptr, 512, qk_scale);
    gemm_bf16<0><<<dim3(32, BB * 16), dim3(256), 0, stream>>>(Ax, Wkp, (void*)Kg, nullptr, 512, qk_scale);
    gemm_bf16<1><<<dim3(32, BB * 16), dim3(256), 0, stream>>>(Ax, Wvp, (void*)Vtg, nullptr, 512, 1.0f);

    attn_kernel<<<dim3(32 * BB * 8), dim3(256), 0, stream>>>(Qg, Kg, Vtg, Og, BB);

    gemm_bf16<2><<<dim3(4, BB * 16), dim3(256), 0, stream>>>(
        Og, Wot, (void*)(out + (size_t)c * BB * 2048 * 512), bo, 4096, 1.0f);
  }
}